// Round 8
// baseline (12343.177 us; speedup 1.0000x reference)
//
#include <hip/hip_runtime.h>

// MANN/NTM encoder, MI355X persistent kernel, round 11 (= r9 + compile fix).
// Root cause of rounds 5-7 failures found: pack_pair(float,float,u32&,u32&)
// called with ext_vector elements (hiv[i]) -> "non-const reference cannot
// bind to vector element". The two "container failed" rounds were this same
// compile failure. Fix: pack2() returns {hi,lo} by value; call sites assign.
//
// Structure (r7): LSTM pointwise lives in B.
//  * A (32 WGs): pure gates-GEMM engine. Publishes gate PRE-ACTIVATIONS
//    Apart[b][2048] = bias + emb-part + h-part + r-part (fp32, coalesced).
//    h/r arrive as bf16 hi/lo packs (no pack_hilo on path). h-part runs
//    speculatively against B's previous step; rflag consumed after it.
//  * B (128 WGs, 1/batch): on-path = poll pflag -> ONE f4 uncached load ->
//    LSTM pointwise (~60 VALU) -> h pack publish (wave0, 2 coalesced stores
//    /thread) -> drain -> hflag. Keys GEMV (h LOCAL), softmax, read, r-pack
//    publish (rflag), memory update, emb prefetch: all off-path.
// Cycle: {pflag: A->B} + {hflag: B->A}; rflag overlapped.
// Flag protocol: relaxed system atomics + s_waitcnt vmcnt(0) drain.

#define T_STEPS 256
#define BSZ     128
#define IDIM    512
#define CDIM    512
#define MW      64
#define G4      2048
#define ODIM    576

typedef unsigned short u16;
typedef unsigned int   u32;
typedef short  short8  __attribute__((ext_vector_type(8)));
typedef float  floatx4 __attribute__((ext_vector_type(4)));
typedef float  f4      __attribute__((ext_vector_type(4)));
typedef u32    u32x4   __attribute__((ext_vector_type(4)));

__device__ __forceinline__ float bf2f(u16 h){ return __uint_as_float(((u32)h)<<16); }
__device__ __forceinline__ u16   f2bf(float f){ u32 u = __float_as_uint(f); return (u16)((u + 0x7fffu + ((u>>16)&1u))>>16); }
__device__ __forceinline__ float sigm(float x){ return 1.f/(1.f+__expf(-x)); }

// coherent-point (L2-bypass) data movement — no cache maintenance
__device__ __forceinline__ f4    vld4 (const float* p){ return *(const volatile f4*)p; }
__device__ __forceinline__ u32x4 vldu4(const u32* p)  { return *(const volatile u32x4*)p; }
__device__ __forceinline__ void  vst4 (float* p, f4 v){ *(volatile f4*)p = v; }
__device__ __forceinline__ void  vstu4(u32* p, u32x4 v){ *(volatile u32x4*)p = v; }

__device__ __forceinline__ void flag_set(u32* p, u32 v){
    __hip_atomic_store(p, v, __ATOMIC_RELAXED, __HIP_MEMORY_SCOPE_SYSTEM);
}
__device__ __forceinline__ void flag_wait(u32* p, u32 v){
    while (__hip_atomic_load(p, __ATOMIC_RELAXED, __HIP_MEMORY_SCOPE_SYSTEM) < v)
        __builtin_amdgcn_s_sleep(2);
}
#define VMDRAIN() asm volatile("s_waitcnt vmcnt(0)" ::: "memory")
#define CBAR()    asm volatile("" ::: "memory")

struct u32pair { u32 hi, lo; };
__device__ __forceinline__ u32pair pack2(float a, float b){
    u16 ha = f2bf(a), hb = f2bf(b);
    u16 la = f2bf(a - bf2f(ha)), lb = f2bf(b - bf2f(hb));
    u32pair r;
    r.hi = (u32)ha | ((u32)hb<<16);
    r.lo = (u32)la | ((u32)lb<<16);
    return r;
}

// ---------------- prep kernels ----------------

__global__ void prep_wt(const float* __restrict__ wih, const float* __restrict__ whh,
                        const float* __restrict__ bih, const float* __restrict__ bhh,
                        u16* __restrict__ WT, float* __restrict__ biasp){
    int idx = blockIdx.x*256 + threadIdx.x;          // 136*2048 = 278528
    if (idx >= 136*G4) return;
    int j  = idx & (G4-1);
    int kg = idx >> 11;
    int ro = (j&3)*512 + (j>>2);
    u32 ohi[4], olo[4];
    #pragma unroll
    for (int p=0;p<4;p++){
        int k0 = kg*8 + p*2;
        float v0 = (k0   < 576) ? wih[ro*576 + k0  ] : whh[ro*512 + k0   - 576];
        float v1 = (k0+1 < 576) ? wih[ro*576 + k0+1] : whh[ro*512 + k0+1 - 576];
        u32pair pp = pack2(v0, v1);
        ohi[p] = pp.hi;
        olo[p] = pp.lo;
    }
    *(uint4*)&WT[(size_t)idx*16]     = make_uint4(ohi[0],ohi[1],ohi[2],ohi[3]);
    *(uint4*)&WT[(size_t)idx*16 + 8] = make_uint4(olo[0],olo[1],olo[2],olo[3]);
    if (idx < G4) biasp[j] = bih[ro] + bhh[ro];
}

// Wk: key-GEMV layout (r4-proven): Wk[(d4)*256 + key] = uint2 of 4 bf16 dims.
__global__ void prep_misc(const float* __restrict__ Wrk, const float* __restrict__ Wwk,
                          const float* __restrict__ We,  const float* __restrict__ Wa,
                          const float* __restrict__ brk, const float* __restrict__ bwk,
                          const float* __restrict__ be,  const float* __restrict__ ba,
                          const float* __restrict__ h0,  const float* __restrict__ r0,
                          u16* __restrict__ Wk, float* __restrict__ kb,
                          u32* __restrict__ hpackhi, u32* __restrict__ hpacklo,
                          u32* __restrict__ rpackhi, u32* __restrict__ rpacklo,
                          u32* __restrict__ pflag, u32* __restrict__ hflag,
                          u32* __restrict__ rflag){
    int idx = blockIdx.x*256 + threadIdx.x;          // grid 512*256 = 131072
    if (idx < 32768) {
        int d4 = idx >> 8, k = idx & 255;
        const float* src = (k<64)? Wrk + k*512 : (k<128)? Wwk + (k-64)*512
                         : (k<192)? We + (k-128)*512 : Wa + (k-192)*512;
        u32 a = (u32)f2bf(src[d4*4+0]) | ((u32)f2bf(src[d4*4+1])<<16);
        u32 b = (u32)f2bf(src[d4*4+2]) | ((u32)f2bf(src[d4*4+3])<<16);
        *(uint2*)&Wk[(size_t)idx*4] = make_uint2(a,b);
    } else if (idx < 33024) {
        int k = idx - 32768;
        kb[k] = (k<64)? brk[k] : (k<128)? bwk[k-64] : (k<192)? be[k-128] : ba[k-192];
    } else if (idx < 65792) {
        int i = idx - 33024;                  // [0,32768): b = i>>8, k2 = i&255
        int k2 = i & 255;
        u32pair pp = pack2(h0[2*k2], h0[2*k2+1]);
        hpackhi[i] = pp.hi; hpacklo[i] = pp.lo;  // h_{-1} broadcast to batches
    } else if (idx < 69888) {
        int i = idx - 65792;                  // [0,4096): b = i>>5, k2 = i&31
        int k2 = i & 31;
        u32pair pp = pack2(r0[2*k2], r0[2*k2+1]);
        rpackhi[i] = pp.hi; rpacklo[i] = pp.lo;  // r_{-1}
    } else if (idx < 70400) {
        pflag[idx - 69888] = 0u;
    } else if (idx < 72448) {
        hflag[idx - 70400] = 0u;
    } else if (idx < 74496) {
        rflag[idx - 72448] = 0u;
    }
}

// ---------------- persistent kernel ----------------

__device__ __forceinline__ short8 pack_hi8(f4 a, f4 b){
    union { short8 s; u16 u[8]; } r;
    r.u[0]=f2bf(a[0]); r.u[1]=f2bf(a[1]); r.u[2]=f2bf(a[2]); r.u[3]=f2bf(a[3]);
    r.u[4]=f2bf(b[0]); r.u[5]=f2bf(b[1]); r.u[6]=f2bf(b[2]); r.u[7]=f2bf(b[3]);
    return r.s;
}

// fused 2-value block reductions over 512 threads (8 waves)
__device__ __forceinline__ void blkMax2(float& va, float& vb, float* red){
    #pragma unroll
    for (int o=32;o;o>>=1){ va = fmaxf(va, __shfl_xor(va,o,64)); vb = fmaxf(vb, __shfl_xor(vb,o,64)); }
    int wv = threadIdx.x >> 6;
    if ((threadIdx.x & 63) == 0){ red[wv] = va; red[8+wv] = vb; }
    __syncthreads();
    float ra = red[0], rb = red[8];
    #pragma unroll
    for (int i=1;i<8;i++){ ra = fmaxf(ra, red[i]); rb = fmaxf(rb, red[8+i]); }
    va = ra; vb = rb;
}
__device__ __forceinline__ void blkSum2(float& va, float& vb, float* red){
    #pragma unroll
    for (int o=32;o;o>>=1){ va += __shfl_xor(va,o,64); vb += __shfl_xor(vb,o,64); }
    int wv = threadIdx.x >> 6;
    if ((threadIdx.x & 63) == 0){ red[wv] = va; red[8+wv] = vb; }
    __syncthreads();
    float ra = red[0], rb = red[8];
    #pragma unroll
    for (int i=1;i<8;i++){ ra += red[i]; rb += red[8+i]; }
    va = ra; vb = rb;
}

// one key's 256-dim half-GEMV from an LDS-staged source, Wk L2-resident
__device__ __forceinline__ float key_gemv(const float* src, const u16* __restrict__ Wk,
                                          int key, int d0){
    const uint2* wp = (const uint2*)Wk;
    float a0=0.f, a1=0.f, a2=0.f, a3=0.f;
    #pragma unroll 8
    for (int dd = 0; dd < 256; dd += 4) {
        uint2 wv2 = wp[((d0+dd)>>2)*256 + key];
        a0 += src[d0+dd+0]*bf2f((u16)(wv2.x & 0xffffu));
        a1 += src[d0+dd+1]*bf2f((u16)(wv2.x >> 16));
        a2 += src[d0+dd+2]*bf2f((u16)(wv2.y & 0xffffu));
        a3 += src[d0+dd+3]*bf2f((u16)(wv2.y >> 16));
    }
    return (a0+a1)+(a2+a3);
}

#define BSTEP ((size_t)(4*G4*16))

// emb-part of the gates GEMM (K=512, 2-term); inits acc to the bias.
__device__ __forceinline__ void emb_part(floatx4 acc[4], const float* embrow,
                                         const u16* __restrict__ bp0,
                                         const float* biasr){
    #pragma unroll
    for (int tl=0;tl<4;tl++){ float bv = biasr[tl];
        acc[tl][0]=bv; acc[tl][1]=bv; acc[tl][2]=bv; acc[tl][3]=bv; }
    #pragma unroll 2
    for (int ks = 0; ks < 16; ++ks) {
        f4 e0 = *(const f4*)(embrow + ks*32);
        f4 e1 = *(const f4*)(embrow + ks*32 + 4);
        short8 af = pack_hi8(e0, e1);
        const u16* bks = bp0 + (size_t)ks*BSTEP;
        #pragma unroll
        for (int tl = 0; tl < 4; ++tl) {
            short8 bh = *(const short8*)(bks + tl*256);
            short8 bl = *(const short8*)(bks + tl*256 + 8);
            acc[tl] = __builtin_amdgcn_mfma_f32_16x16x32_bf16(af, bh, acc[tl], 0,0,0);
            acc[tl] = __builtin_amdgcn_mfma_f32_16x16x32_bf16(af, bl, acc[tl], 0,0,0);
        }
    }
}

__launch_bounds__(512)
__global__ void mann_persist(const float* __restrict__ embs, const u16* __restrict__ WT,
                             const float* __restrict__ biasp, const u16* __restrict__ Wk,
                             const float* __restrict__ kbias,
                             float* __restrict__ Apart,
                             u32* __restrict__ hpackhi, u32* __restrict__ hpacklo,
                             u32* __restrict__ rpackhi, u32* __restrict__ rpacklo,
                             const float* __restrict__ mem0, const float* __restrict__ c0,
                             float* __restrict__ out,
                             u32* __restrict__ pflag, u32* __restrict__ hflag,
                             u32* __restrict__ rflag){
    __shared__ __align__(16) char smraw[140800];
    float* sp = (float*)smraw;
    const int w = blockIdx.x;
    const int tid = threadIdx.x;
    if (w >= 160) return;

    if (w < 128) {
        // ================= B role: one WG per batch =========================
        float* part  = sp;           // [512][65] read-reduction staging
        float* gsc   = sp + 33280;   // [512] GEMV partials / reduce scratch
        float* keys  = sp + 33792;   // [256] k_r | k_w | e | a
        float* red   = sp + 34048;   // [32]
        float* h_lds = sp + 34080;   // [512] h_t (fp32, local)
        float* ebb   = sp + 34592;   // [512] emb_t
        float* r_lds = sp + 35104;   // [64]  r_t
        const int b = w;
        const int bgrp4 = (b>>4)*4;
        const int key = tid & 255, kh = tid >> 8, d0 = kh*256;
        const int n0 = tid*2;        // this thread owns memory rows n0, n0+1

        float m0[64], m1[64];
        #pragma unroll
        for (int m4=0;m4<16;m4++){
            f4 v0 = *(const f4*)(mem0 + (size_t)n0*64 + m4*4);
            f4 v1 = *(const f4*)(mem0 + (size_t)(n0+1)*64 + m4*4);
            #pragma unroll
            for (int j=0;j<4;j++){ m0[m4*4+j] = v0[j]; m1[m4*4+j] = v1[j]; }
        }
        float c = c0[tid];           // cell state for n = tid

        // preloop: emb_0 + a-key partials (consumed by step 0's keys combine)
        ebb[tid] = embs[(size_t)b*IDIM + tid];
        __syncthreads();
        if (key >= 192) gsc[tid] = key_gemv(ebb, Wk, key, d0);

        for (int t = 0; t < T_STEPS; ++t) {
            // ---------------- on-path: gates -> h -> publish ----------------
            if (tid < 4) flag_wait(&pflag[(bgrp4 + tid)*16], (u32)(t+1));
            __syncthreads();
            CBAR();
            f4 g4 = vld4(Apart + (size_t)b*G4 + tid*4);   // (i,f,g,o) for n=tid
            c = sigm(g4[1])*c + sigm(g4[0])*tanhf(g4[2]);
            float hn = sigm(g4[3])*tanhf(c);
            h_lds[tid] = hn;
            __syncthreads();
            if (tid < 64) {          // wave 0 only: pack + publish, coalesced
                u32x4 hiv, lov;
                u32pair p0 = pack2(h_lds[tid*8+0], h_lds[tid*8+1]);
                u32pair p1 = pack2(h_lds[tid*8+2], h_lds[tid*8+3]);
                u32pair p2 = pack2(h_lds[tid*8+4], h_lds[tid*8+5]);
                u32pair p3 = pack2(h_lds[tid*8+6], h_lds[tid*8+7]);
                hiv[0]=p0.hi; hiv[1]=p1.hi; hiv[2]=p2.hi; hiv[3]=p3.hi;
                lov[0]=p0.lo; lov[1]=p1.lo; lov[2]=p2.lo; lov[3]=p3.lo;
                vstu4(hpackhi + (size_t)b*256 + tid*4, hiv);
                vstu4(hpacklo + (size_t)b*256 + tid*4, lov);
                VMDRAIN();
                if (tid == 0) flag_set(&hflag[b*16], (u32)(t+1));
            }

            // ---------------- off-path (overlaps A's next h-part) -----------
            if (tid < 128)           // out h (coalesced f4)
                *(f4*)(out + ((size_t)(t*BSZ + b))*ODIM + tid*4) = *(const f4*)&h_lds[tid*4];
            if (key < 192) gsc[tid] = key_gemv(h_lds, Wk, key, d0);
            __syncthreads();
            if (tid < 256) {
                float kv = kbias[tid] + gsc[tid] + gsc[tid+256];
                if (tid >= 192)      kv = tanhf(kv);
                else if (tid >= 128) kv = sigm(kv);
                keys[tid] = kv;
            }
            __syncthreads();

            // content scores from register-resident memory rows
            float s0r=0.f, s0w=0.f, s1r=0.f, s1w=0.f;
            #pragma unroll
            for (int m4=0;m4<16;m4++){
                f4 kr = *(const f4*)&keys[m4*4];
                f4 kw = *(const f4*)&keys[64 + m4*4];
                #pragma unroll
                for (int j=0;j<4;j++){
                    s0r += m0[m4*4+j]*kr[j]; s1r += m1[m4*4+j]*kr[j];
                    s0w += m0[m4*4+j]*kw[j]; s1w += m1[m4*4+j]*kw[j];
                }
            }
            float Mr = fmaxf(s0r, s1r), Mw = fmaxf(s0w, s1w);
            blkMax2(Mr, Mw, red);
            float e0r = __expf(s0r - Mr), e1r = __expf(s1r - Mr);
            float e0w = __expf(s0w - Mw), e1w = __expf(s1w - Mw);
            float Sr = e0r + e1r, Sw = e0w + e1w;
            blkSum2(Sr, Sw, red + 16);

            // read r = sum_n w_r[n] mem[n][:]  (padded LDS tile, stride 65)
            float* prow = part + tid*65;
            #pragma unroll
            for (int m=0;m<64;m++) prow[m] = e0r*m0[m] + e1r*m1[m];
            __syncthreads();
            {
                int mm = tid & 63, blk = tid >> 6;
                const float* pb2 = part + (size_t)blk*64*65 + mm;
                float s = 0.f;
                #pragma unroll
                for (int r=0;r<64;r++) s += pb2[r*65];
                gsc[tid] = s;
            }
            __syncthreads();
            if (tid < 64) {
                float rv = 0.f;
                #pragma unroll
                for (int k=0;k<8;k++) rv += gsc[k*64 + tid];
                rv /= Sr;
                r_lds[tid] = rv;
            }
            __syncthreads();
            if (tid < 8) {           // wave 0: pack + publish r (coalesced)
                u32x4 hiv, lov;
                u32pair p0 = pack2(r_lds[tid*8+0], r_lds[tid*8+1]);
                u32pair p1 = pack2(r_lds[tid*8+2], r_lds[tid*8+3]);
                u32pair p2 = pack2(r_lds[tid*8+4], r_lds[tid*8+5]);
                u32pair p3 = pack2(r_lds[tid*8+6], r_lds[tid*8+7]);
                hiv[0]=p0.hi; hiv[1]=p1.hi; hiv[2]=p2.hi; hiv[3]=p3.hi;
                lov[0]=p0.lo; lov[1]=p1.lo; lov[2]=p2.lo; lov[3]=p3.lo;
                vstu4(rpackhi + (size_t)b*32 + tid*4, hiv);
                vstu4(rpacklo + (size_t)b*32 + tid*4, lov);
                VMDRAIN();
                if (tid == 0) flag_set(&rflag[b*16], (u32)(t+1));
            }
            if (tid < 64)
                out[((size_t)(t*BSZ + b))*ODIM + 512 + tid] = r_lds[tid];

            // erase/add memory update (registers only)
            float iSw = 1.f / Sw;
            float w0 = e0w*iSw, w1 = e1w*iSw;
            #pragma unroll
            for (int m4=0;m4<16;m4++){
                f4 ev = *(const f4*)&keys[128 + m4*4];
                f4 av = *(const f4*)&keys[192 + m4*4];
                #pragma unroll
                for (int j=0;j<4;j++){
                    m0[m4*4+j] = m0[m4*4+j]*(1.f - w0*ev[j]) + w0*av[j];
                    m1[m4*4+j] = m1[m4*4+j]*(1.f - w1*ev[j]) + w1*av[j];
                }
            }
            // emb prefetch + a-key partials for t+1
            if (t + 1 < T_STEPS) {
                ebb[tid] = embs[((size_t)((t+1)*BSZ + b))*IDIM + tid];
                __syncthreads();
                if (key >= 192) gsc[tid] = key_gemv(ebb, Wk, key, d0);
            }
        }
    } else {
        // ================= A role: 32 gate-GEMM WGs =========================
        // LDS: hih [16][260] u32, hil [16][260] u32 (260 = 256 + 4 pad),
        //      Ap_lds [16][516] float
        u32*   hih   = (u32*)sp;             // 4160 u32
        u32*   hil   = (u32*)sp + 4160;      // 4160 u32
        float* Ap_lds= sp + 8320;            // 8256 floats
        const int a = w - 128, bgrp = a >> 2, cgrp = a & 3;
        const int lane = tid & 63, wv = tid >> 6, jl = lane & 15, q = lane >> 4;
        const int colbase = cgrp*512 + wv*64;
        const int bA = bgrp*16 + jl;
        const u16* bp0 = WT + ((size_t)q*G4 + colbase + jl)*16;

        float biasr[4];
        #pragma unroll
        for (int tl=0; tl<4; ++tl) biasr[tl] = biasp[colbase + tl*16 + jl];

        floatx4 acc[4];
        emb_part(acc, embs + (size_t)bA*IDIM + q*8, bp0, biasr);  // t = 0

        for (int t = 0; t < T_STEPS; ++t) {
            // ---- speculative vs B's step t-1: stage h pack + h-part --------
            if (tid < 16) flag_wait(&hflag[(bgrp*16 + tid)*16], (u32)t);
            __syncthreads();
            CBAR();
            {   // stage 16 batches x 256 u32 (hi+lo), coalesced
                int i0 = tid*8, b16 = i0 >> 8, k2 = i0 & 255;
                const size_t g = (size_t)(bgrp*16 + b16)*256 + k2;
                u32x4 h0v = vldu4(hpackhi + g), h1v = vldu4(hpackhi + g + 4);
                u32x4 l0v = vldu4(hpacklo + g), l1v = vldu4(hpacklo + g + 4);
                *(u32x4*)&hih[b16*260 + k2]     = h0v;
                *(u32x4*)&hih[b16*260 + k2 + 4] = h1v;
                *(u32x4*)&hil[b16*260 + k2]     = l0v;
                *(u32x4*)&hil[b16*260 + k2 + 4] = l1v;
            }
            __syncthreads();
            #pragma unroll 2
            for (int ks = 18; ks < 34; ++ks) {              // h-part, 3-term
                int du = (ks-18)*16 + q*4;                  // u32 index
                short8 ah = *(const short8*)&hih[jl*260 + du];
                short8 al = *(const short8*)&hil[jl*260 + du];
                const u16* bks = bp0 + (size_t)ks*BSTEP;
                #pragma unroll
                for (int tl = 0; tl < 4; ++tl) {
                    short8 bh = *(const short8*)(bks + tl*256);
                    short8 bl = *(const short8*)(bks + tl*256 + 8);
                    acc[tl] = __builtin_amdgcn_mfma_f32_16x16x32_bf16(ah, bh, acc[tl], 0,0,0);
                    acc[tl] = __builtin_amdgcn_mfma_f32_16x16x32_bf16(al, bh, acc[tl], 0,0,0);
                    acc[tl] = __builtin_amdgcn_mfma_f32_16x16x32_bf16(ah, bl, acc[tl], 0,0,0);
                }
            }

            // ---- critical: rflag -> r-part -> publish Apart ----------------
            if (tid < 16) flag_wait(&rflag[(bgrp*16 + tid)*16], (u32)t);
            __syncthreads();
            CBAR();
            #pragma unroll
            for (int ks = 16; ks < 18; ++ks) {              // r-part, 3-term
                const size_t g = (size_t)bA*32 + (ks-16)*16 + q*4;
                union { u32x4 u; short8 s; } th, tl4;
                th.u  = vldu4(rpackhi + g);
                tl4.u = vldu4(rpacklo + g);
                short8 ah = th.s, al = tl4.s;
                const u16* bks = bp0 + (size_t)ks*BSTEP;
                #pragma unroll
                for (int tl = 0; tl < 4; ++tl) {
                    short8 bh = *(const short8*)(bks + tl*256);
                    short8 bl = *(const short8*)(bks + tl*256 + 8);
                    acc[tl] = __builtin_amdgcn_mfma_f32_16x16x32_bf16(ah, bh, acc[tl], 0,0,0);
                    acc[tl] = __builtin_amdgcn_mfma_f32_16x16x32_bf16(al, bh, acc[tl], 0,0,0);
                    acc[tl] = __builtin_amdgcn_mfma_f32_16x16x32_bf16(ah, bl, acc[tl], 0,0,0);
                }
            }
            // epilogue: acc -> LDS tile [batch16][512] (row = q*4+rg)
            #pragma unroll
            for (int tl = 0; tl < 4; ++tl) {
                int cl = wv*64 + tl*16 + jl;
                #pragma unroll
                for (int rg = 0; rg < 4; ++rg)
                    Ap_lds[(q*4+rg)*516 + cl] = acc[tl][rg];
            }
            __syncthreads();
            {   // coalesced publish: 16 batches x 512 cols, 4x vst4/thread
                #pragma unroll
                for (int p = 0; p < 4; ++p) {
                    int flat = p*2048 + tid*4;
                    int row = flat >> 9, col = flat & 511;
                    f4 v = *(const f4*)&Ap_lds[row*516 + col];
                    vst4(Apart + (size_t)(bgrp*16 + row)*G4 + cgrp*512 + col, v);
                }
            }
            VMDRAIN();
            __syncthreads();
            if (tid == 0) flag_set(&pflag[a*16], (u32)(t+1));

            // ---- off-path: emb-part (+bias) for t+1 ------------------------
            if (t + 1 < T_STEPS)
                emb_part(acc, embs + ((size_t)((t+1)*BSZ + bA))*IDIM + q*8,
                         bp0, biasr);
        }
    }
}

// ---------------- launch ----------------

#define OFF_WT     0u
#define OFF_BIASP  8912896u
#define OFF_WK     8921088u
#define OFF_KBIAS  9183232u
#define OFF_APART  9184256u
#define OFF_HPH    10232832u
#define OFF_HPL    10363904u
#define OFF_RPH    10494976u
#define OFF_RPL    10511360u
#define OFF_PFLAG  10527744u
#define OFF_HFLAG  10529792u
#define OFF_RFLAG  10537984u
#define WS_NEED    10546176u

extern "C" void kernel_launch(void* const* d_in, const int* in_sizes, int n_in,
                              void* d_out, int out_size, void* d_ws, size_t ws_size,
                              hipStream_t stream) {
    if (ws_size < (size_t)WS_NEED) return;

    const float* embs = (const float*)d_in[0];
    const float* w_ih = (const float*)d_in[1];
    const float* w_hh = (const float*)d_in[2];
    const float* b_ih = (const float*)d_in[3];
    const float* b_hh = (const float*)d_in[4];
    const float* h0   = (const float*)d_in[5];
    const float* c0   = (const float*)d_in[6];
    const float* r0   = (const float*)d_in[7];
    const float* mem0 = (const float*)d_in[8];
    const float* Wrk  = (const float*)d_in[9];
    const float* brk  = (const float*)d_in[10];
    const float* Wwk  = (const float*)d_in[11];
    const float* bwk  = (const float*)d_in[12];
    const float* We   = (const float*)d_in[13];
    const float* be   = (const float*)d_in[14];
    const float* Wa   = (const float*)d_in[15];
    const float* ba   = (const float*)d_in[16];

    char* ws = (char*)d_ws;
    u16*   WT    = (u16*)  (ws + OFF_WT);
    float* biasp = (float*)(ws + OFF_BIASP);
    u16*   Wk    = (u16*)  (ws + OFF_WK);
    float* kbias = (float*)(ws + OFF_KBIAS);
    float* Apart = (float*)(ws + OFF_APART);
    u32*   hph   = (u32*)  (ws + OFF_HPH);
    u32*   hpl   = (u32*)  (ws + OFF_HPL);
    u32*   rph   = (u32*)  (ws + OFF_RPH);
    u32*   rpl   = (u32*)  (ws + OFF_RPL);
    u32*   pflag = (u32*)  (ws + OFF_PFLAG);
    u32*   hflag = (u32*)  (ws + OFF_HFLAG);
    u32*   rflag = (u32*)  (ws + OFF_RFLAG);
    float* outp  = (float*)d_out;

    hipLaunchKernelGGL(prep_wt,   dim3(1088), dim3(256), 0, stream,
                       w_ih, w_hh, b_ih, b_hh, WT, biasp);
    hipLaunchKernelGGL(prep_misc, dim3(512),  dim3(256), 0, stream,
                       Wrk, Wwk, We, Wa, brk, bwk, be, ba, h0, r0,
                       Wk, kbias, hph, hpl, rph, rpl, pflag, hflag, rflag);

    const float* embs_c = embs; const u16* WT_c = WT; const float* biasp_c = biasp;
    const u16* Wk_c = Wk; const float* kbias_c = kbias;
    const float* mem0_c = mem0; const float* c0_c = c0;
    void* kargs[] = { (void*)&embs_c, (void*)&WT_c, (void*)&biasp_c, (void*)&Wk_c,
                      (void*)&kbias_c, (void*)&Apart, (void*)&hph, (void*)&hpl,
                      (void*)&rph, (void*)&rpl, (void*)&mem0_c, (void*)&c0_c,
                      (void*)&outp, (void*)&pflag, (void*)&hflag, (void*)&rflag };
    hipLaunchCooperativeKernel((void*)mann_persist, dim3(160), dim3(512), kargs, 0, stream);
}

// Round 9
// 8665.981 us; speedup vs baseline: 1.4243x; 1.4243x over previous
//
#include <hip/hip_runtime.h>

// MANN/NTM encoder, MI355X persistent kernel, round 12 = r4 revert + deltas.
// r11 post-mortem: Apart fp32 handoff quadrupled uncached-hop bytes ->
// hbm_bytes 0.49->7.1 GB, 12.3 ms (worse than r4's 8.78). The UC data plane
// is priced per byte; r4's h/r plane is near-minimal. This round = r4 plus:
//  1. agent-scope flags (sc0-read/sc1-write at MALL, not system-to-memory)
//  2. A: r-part staged per-lane from xr (kills rst LDS hop on critical path)
//  3. A: epilogue transcendentals by lane gate-type + biases in registers
// Structure (r4): A (32 WGs) = gates GEMM + LSTM epilogue, h-part speculative
// vs B's previous step; B (128 WGs, 1/batch) = keys GEMV + softmax + read +
// erase/add with NTM memory in VGPRs; out/mem-update off-path.
// Flag DAG: A waits {own-group hflag(t), rflag(t)}; B waits hflag(t+1).

#define T_STEPS 256
#define BSZ     128
#define IDIM    512
#define CDIM    512
#define MW      64
#define G4      2048
#define ODIM    576

typedef unsigned short u16;
typedef unsigned int   u32;
typedef short  short8  __attribute__((ext_vector_type(8)));
typedef float  floatx4 __attribute__((ext_vector_type(4)));
typedef float  f4      __attribute__((ext_vector_type(4)));

__device__ __forceinline__ float bf2f(u16 h){ return __uint_as_float(((u32)h)<<16); }
__device__ __forceinline__ u16   f2bf(float f){ u32 u = __float_as_uint(f); return (u16)((u + 0x7fffu + ((u>>16)&1u))>>16); }
__device__ __forceinline__ float sigm(float x){ return 1.f/(1.f+__expf(-x)); }

// coherent-point (L2-bypass) data movement — no cache maintenance
__device__ __forceinline__ f4 vld4(const float* p){ return *(const volatile f4*)p; }
__device__ __forceinline__ float vldf(const float* p){ return *(const volatile float*)p; }
__device__ __forceinline__ void vstf(float* p, float v){ *(volatile float*)p = v; }
__device__ __forceinline__ void vst4(float* p, f4 v){ *(volatile f4*)p = v; }

// flags: agent scope (single-GPU coherence point = MALL; shorter than system)
__device__ __forceinline__ void flag_set(u32* p, u32 v){
    __hip_atomic_store(p, v, __ATOMIC_RELAXED, __HIP_MEMORY_SCOPE_AGENT);
}
__device__ __forceinline__ void flag_wait(u32* p, u32 v){
    while (__hip_atomic_load(p, __ATOMIC_RELAXED, __HIP_MEMORY_SCOPE_AGENT) < v)
        __builtin_amdgcn_s_sleep(2);
}
#define VMDRAIN() asm volatile("s_waitcnt vmcnt(0)" ::: "memory")
#define CBAR()    asm volatile("" ::: "memory")

// ---------------- prep kernels (r4 verbatim) ----------------

__global__ void prep_wt(const float* __restrict__ wih, const float* __restrict__ whh,
                        const float* __restrict__ bih, const float* __restrict__ bhh,
                        u16* __restrict__ WT, float* __restrict__ biasp){
    int idx = blockIdx.x*256 + threadIdx.x;          // 136*2048 = 278528
    if (idx >= 136*G4) return;
    int j  = idx & (G4-1);
    int kg = idx >> 11;
    int ro = (j&3)*512 + (j>>2);
    u32 ohi[4], olo[4];
    #pragma unroll
    for (int p=0;p<4;p++){
        int k0 = kg*8 + p*2;
        float v0 = (k0   < 576) ? wih[ro*576 + k0  ] : whh[ro*512 + k0   - 576];
        float v1 = (k0+1 < 576) ? wih[ro*576 + k0+1] : whh[ro*512 + k0+1 - 576];
        u16 h0b = f2bf(v0), h1b = f2bf(v1);
        u16 l0b = f2bf(v0 - bf2f(h0b)), l1b = f2bf(v1 - bf2f(h1b));
        ohi[p] = (u32)h0b | ((u32)h1b<<16);
        olo[p] = (u32)l0b | ((u32)l1b<<16);
    }
    *(uint4*)&WT[(size_t)idx*16]     = make_uint4(ohi[0],ohi[1],ohi[2],ohi[3]);
    *(uint4*)&WT[(size_t)idx*16 + 8] = make_uint4(olo[0],olo[1],olo[2],olo[3]);
    if (idx < G4) biasp[j] = bih[ro] + bhh[ro];
}

__global__ void prep_misc(const float* __restrict__ Wrk, const float* __restrict__ Wwk,
                          const float* __restrict__ We,  const float* __restrict__ Wa,
                          const float* __restrict__ brk, const float* __restrict__ bwk,
                          const float* __restrict__ be,  const float* __restrict__ ba,
                          const float* __restrict__ h0,  const float* __restrict__ r0,
                          u16* __restrict__ Wk, float* __restrict__ kb,
                          float* __restrict__ hbuf, float* __restrict__ xr,
                          u32* __restrict__ hflag, u32* __restrict__ rflag,
                          u32* __restrict__ pflag){
    int idx = blockIdx.x*256 + threadIdx.x;          // grid 512*256 = 131072
    if (idx < 32768) {
        int d4 = idx >> 8, k = idx & 255;
        const float* src = (k<64)? Wrk + k*512 : (k<128)? Wwk + (k-64)*512
                         : (k<192)? We + (k-128)*512 : Wa + (k-192)*512;
        u32 a = (u32)f2bf(src[d4*4+0]) | ((u32)f2bf(src[d4*4+1])<<16);
        u32 b = (u32)f2bf(src[d4*4+2]) | ((u32)f2bf(src[d4*4+3])<<16);
        *(uint2*)&Wk[(size_t)idx*4] = make_uint2(a,b);
    } else if (idx < 33024) {
        int k = idx - 32768;
        kb[k] = (k<64)? brk[k] : (k<128)? bwk[k-64] : (k<192)? be[k-128] : ba[k-192];
    } else if (idx < 98560) {
        int i = idx - 33024;
        hbuf[65536 + i] = h0[i & 511];               // slot 1 = h_{-1}
    } else if (idx < 106752) {
        int i = idx - 98560;
        xr[i] = r0[i & 63];
    } else if (idx < 107776) {
        hflag[idx - 106752] = 0u;
    } else if (idx < 109824) {
        rflag[idx - 107776] = 0u;
    } else if (idx < 113920) {
        pflag[idx - 109824] = 0u;
    }
}

// ---------------- persistent kernel ----------------

__device__ __forceinline__ short8 pack_hi(f4 a, f4 b){
    union { short8 s; u16 u[8]; } r;
    r.u[0]=f2bf(a[0]); r.u[1]=f2bf(a[1]); r.u[2]=f2bf(a[2]); r.u[3]=f2bf(a[3]);
    r.u[4]=f2bf(b[0]); r.u[5]=f2bf(b[1]); r.u[6]=f2bf(b[2]); r.u[7]=f2bf(b[3]);
    return r.s;
}
__device__ __forceinline__ void pack_hilo(f4 a, f4 b, short8& hh, short8& ll){
    union { short8 s; u16 u[8]; } H, L;
    float v[8] = {a[0],a[1],a[2],a[3],b[0],b[1],b[2],b[3]};
    #pragma unroll
    for (int i=0;i<8;i++){ u16 hb = f2bf(v[i]); H.u[i]=hb; L.u[i]=f2bf(v[i]-bf2f(hb)); }
    hh = H.s; ll = L.s;
}

// fused 2-value block reductions over 512 threads (8 waves)
__device__ __forceinline__ void blkMax2(float& va, float& vb, float* red){
    #pragma unroll
    for (int o=32;o;o>>=1){ va = fmaxf(va, __shfl_xor(va,o,64)); vb = fmaxf(vb, __shfl_xor(vb,o,64)); }
    int wv = threadIdx.x >> 6;
    if ((threadIdx.x & 63) == 0){ red[wv] = va; red[8+wv] = vb; }
    __syncthreads();
    float ra = red[0], rb = red[8];
    #pragma unroll
    for (int i=1;i<8;i++){ ra = fmaxf(ra, red[i]); rb = fmaxf(rb, red[8+i]); }
    va = ra; vb = rb;
}
__device__ __forceinline__ void blkSum2(float& va, float& vb, float* red){
    #pragma unroll
    for (int o=32;o;o>>=1){ va += __shfl_xor(va,o,64); vb += __shfl_xor(vb,o,64); }
    int wv = threadIdx.x >> 6;
    if ((threadIdx.x & 63) == 0){ red[wv] = va; red[8+wv] = vb; }
    __syncthreads();
    float ra = red[0], rb = red[8];
    #pragma unroll
    for (int i=1;i<8;i++){ ra += red[i]; rb += red[8+i]; }
    va = ra; vb = rb;
}

// one key's 256-dim half-GEMV from an LDS-staged source, Wk L2-resident
__device__ __forceinline__ float key_gemv(const float* src, const u16* __restrict__ Wk,
                                          int key, int d0){
    const uint2* wp = (const uint2*)Wk;
    float a0=0.f, a1=0.f, a2=0.f, a3=0.f;
    #pragma unroll 8
    for (int dd = 0; dd < 256; dd += 4) {
        uint2 wv2 = wp[((d0+dd)>>2)*256 + key];
        a0 += src[d0+dd+0]*bf2f((u16)(wv2.x & 0xffffu));
        a1 += src[d0+dd+1]*bf2f((u16)(wv2.x >> 16));
        a2 += src[d0+dd+2]*bf2f((u16)(wv2.y & 0xffffu));
        a3 += src[d0+dd+3]*bf2f((u16)(wv2.y >> 16));
    }
    return (a0+a1)+(a2+a3);
}

#define BSTEP ((size_t)(4*G4*16))

// emb-part of the gates GEMM (K=512, 2-term); zero-inits acc.
__device__ __forceinline__ void emb_part(floatx4 acc[4], const float* embrow,
                                         const u16* __restrict__ bp0){
    #pragma unroll
    for (int tl=0;tl<4;tl++){ acc[tl][0]=0.f; acc[tl][1]=0.f; acc[tl][2]=0.f; acc[tl][3]=0.f; }
    #pragma unroll 2
    for (int ks = 0; ks < 16; ++ks) {
        f4 e0 = *(const f4*)(embrow + ks*32);
        f4 e1 = *(const f4*)(embrow + ks*32 + 4);
        short8 af = pack_hi(e0, e1);
        const u16* bks = bp0 + (size_t)ks*BSTEP;
        #pragma unroll
        for (int tl = 0; tl < 4; ++tl) {
            short8 bh = *(const short8*)(bks + tl*256);
            short8 bl = *(const short8*)(bks + tl*256 + 8);
            acc[tl] = __builtin_amdgcn_mfma_f32_16x16x32_bf16(af, bh, acc[tl], 0,0,0);
            acc[tl] = __builtin_amdgcn_mfma_f32_16x16x32_bf16(af, bl, acc[tl], 0,0,0);
        }
    }
}

__launch_bounds__(512)
__global__ void mann_persist(const float* __restrict__ embs, const u16* __restrict__ WT,
                             const float* __restrict__ biasp, const u16* __restrict__ Wk,
                             const float* __restrict__ kbias,
                             float* __restrict__ hbuf, float* __restrict__ xr,
                             const float* __restrict__ mem0, const float* __restrict__ c0,
                             float* __restrict__ out,
                             u32* __restrict__ hflag, u32* __restrict__ rflag){
    __shared__ __align__(16) char smraw[140800];
    float* sp = (float*)smraw;
    const int w = blockIdx.x;
    const int tid = threadIdx.x;
    if (w >= 160) return;

    if (w < 128) {
        // ================= B role: one WG per batch, memory in VGPRs =========
        float* part = sp;            // [512][65]  read-reduction staging
        float* gsc  = sp + 33280;    // [512] GEMV partials / reduce scratch
        float* keys = sp + 33792;    // [256] k_r | k_w | e | a
        float* red  = sp + 34048;    // [32]
        float* hb   = sp + 34080;    // [512] h_t
        float* ebb  = sp + 34592;    // [512] emb_t
        const int b = w;
        const int bgrp4 = (b>>4)*4;
        const int key = tid & 255, kh = tid >> 8, d0 = kh*256;
        const int n0 = tid*2;        // this thread owns memory rows n0, n0+1

        float m0[64], m1[64];
        #pragma unroll
        for (int m4=0;m4<16;m4++){
            f4 v0 = *(const f4*)(mem0 + (size_t)n0*64 + m4*4);
            f4 v1 = *(const f4*)(mem0 + (size_t)(n0+1)*64 + m4*4);
            #pragma unroll
            for (int j=0;j<4;j++){ m0[m4*4+j] = v0[j]; m1[m4*4+j] = v1[j]; }
        }

        for (int t = 0; t < T_STEPS; ++t) {
            // emb + a-key GEMV: no h dependency -> overlaps the wait
            ebb[tid] = embs[((size_t)(t*BSZ + b))*IDIM + tid];
            __syncthreads();
            if (key >= 192) gsc[tid] = key_gemv(ebb, Wk, key, d0);
            if (tid < 4) flag_wait(&hflag[(bgrp4 + tid)*32], (u32)(t+1));
            __syncthreads();
            CBAR();
            hb[tid] = vldf(hbuf + (t&1)*65536 + b*CDIM + tid);
            __syncthreads();
            if (key < 192) gsc[tid] = key_gemv(hb, Wk, key, d0);
            __syncthreads();
            if (tid < 256) {
                float acc = kbias[tid] + gsc[tid] + gsc[tid+256];
                if (tid >= 192)      acc = tanhf(acc);
                else if (tid >= 128) acc = sigm(acc);
                keys[tid] = acc;
            }
            __syncthreads();

            // content scores for both keys from register-resident memory rows
            float s0r=0.f, s0w=0.f, s1r=0.f, s1w=0.f;
            #pragma unroll
            for (int m4=0;m4<16;m4++){
                f4 kr = *(const f4*)&keys[m4*4];
                f4 kw = *(const f4*)&keys[64 + m4*4];
                #pragma unroll
                for (int j=0;j<4;j++){
                    s0r += m0[m4*4+j]*kr[j]; s1r += m1[m4*4+j]*kr[j];
                    s0w += m0[m4*4+j]*kw[j]; s1w += m1[m4*4+j]*kw[j];
                }
            }
            float Mr = fmaxf(s0r, s1r), Mw = fmaxf(s0w, s1w);
            blkMax2(Mr, Mw, red);
            float e0r = __expf(s0r - Mr), e1r = __expf(s1r - Mr);
            float e0w = __expf(s0w - Mw), e1w = __expf(s1w - Mw);
            float Sr = e0r + e1r, Sw = e0w + e1w;
            blkSum2(Sr, Sw, red + 16);

            // read partials -> padded LDS tile (stride 65: conflict-free)
            float* prow = part + tid*65;
            #pragma unroll
            for (int m=0;m<64;m++) prow[m] = e0r*m0[m] + e1r*m1[m];
            __syncthreads();
            {
                int mm = tid & 63, blk = tid >> 6;
                const float* pb2 = part + (size_t)blk*64*65 + mm;
                float s = 0.f;
                #pragma unroll
                for (int r=0;r<64;r++) s += pb2[r*65];
                gsc[tid] = s;
            }
            __syncthreads();
            float rv = 0.f;
            if (tid < 64) {
                #pragma unroll
                for (int k=0;k<8;k++) rv += gsc[k*64 + tid];
                rv /= Sr;
                vstf(xr + b*MW + tid, rv);
            }
            VMDRAIN();                                  // writers are wave 0
            if (tid == 0) flag_set(&rflag[b*16], (u32)(t+1));

            // off-path: out r write + erase/add update (registers only)
            if (tid < 64)
                out[((size_t)(t*BSZ + b))*ODIM + 512 + tid] = rv;
            float iSw = 1.f / Sw;
            float w0 = e0w*iSw, w1 = e1w*iSw;
            #pragma unroll
            for (int m4=0;m4<16;m4++){
                f4 ev = *(const f4*)&keys[128 + m4*4];
                f4 av = *(const f4*)&keys[192 + m4*4];
                #pragma unroll
                for (int j=0;j<4;j++){
                    m0[m4*4+j] = m0[m4*4+j]*(1.f - w0*ev[j]) + w0*av[j];
                    m1[m4*4+j] = m1[m4*4+j]*(1.f - w1*ev[j]) + w1*av[j];
                }
            }
        }
    } else {
        // ================= A role: 32 dedicated gates-GEMM WGs ===============
        float* hst  = sp;            // [16][516] staged h_{t-1}
        float* hst2 = sp + 8256;     // [16][128] h_t slice (this WG's 128 cols)
        const int a = w - 128, bgrp = a >> 2, cgrp = a & 3;
        const int lane = tid & 63, wv = tid >> 6, jl = lane & 15, q = lane >> 4;
        const int colbase = cgrp*512 + wv*64;
        const int bA = bgrp*16 + jl;
        const int gl = jl & 3;                     // lane's gate type (i,f,g,o)
        const u16* bp0 = WT + ((size_t)q*G4 + colbase + jl)*16;

        float biasr[4];
        #pragma unroll
        for (int tl=0; tl<4; ++tl) biasr[tl] = biasp[colbase + tl*16 + jl];

        float creg[16];                            // valid on gl==0 lanes only
        #pragma unroll
        for (int tl=0; tl<4; ++tl) {
            float cv = c0[(colbase + tl*16 + jl) >> 2];
            creg[tl*4+0]=cv; creg[tl*4+1]=cv; creg[tl*4+2]=cv; creg[tl*4+3]=cv;
        }
        floatx4 acc[4];
        emb_part(acc, embs + (size_t)bA*IDIM + q*8, bp0);     // t = 0

        for (int t = 0; t < T_STEPS; ++t) {
            // ---- speculative section: overlaps B's phase of step t-1 ----
            if (tid < 4) flag_wait(&hflag[(bgrp*4 + tid)*32], (u32)t);
            __syncthreads();
            CBAR();
            {   // stage h_{t-1}: 16 batches x 512, one volatile burst
                const float* hsrc = hbuf + ((t+1)&1)*65536 + (size_t)bgrp*16*CDIM;
                #pragma unroll
                for (int p=0;p<4;p++){
                    int idx = p*2048 + tid*4;
                    f4 v = vld4(hsrc + idx);
                    *(f4*)&hst[(idx>>9)*516 + (idx&511)] = v;
                }
            }
            __syncthreads();
            #pragma unroll 2
            for (int ks = 18; ks < 34; ++ks) {              // h-part, 3-term
                int d = (ks-18)*32 + q*8;
                f4 h0v = *(const f4*)&hst[jl*516 + d];
                f4 h1v = *(const f4*)&hst[jl*516 + d + 4];
                short8 ah, al; pack_hilo(h0v, h1v, ah, al);
                const u16* bks = bp0 + (size_t)ks*BSTEP;
                #pragma unroll
                for (int tl = 0; tl < 4; ++tl) {
                    short8 bh = *(const short8*)(bks + tl*256);
                    short8 bl = *(const short8*)(bks + tl*256 + 8);
                    acc[tl] = __builtin_amdgcn_mfma_f32_16x16x32_bf16(ah, bh, acc[tl], 0,0,0);
                    acc[tl] = __builtin_amdgcn_mfma_f32_16x16x32_bf16(al, bh, acc[tl], 0,0,0);
                    acc[tl] = __builtin_amdgcn_mfma_f32_16x16x32_bf16(ah, bl, acc[tl], 0,0,0);
                }
            }

            // ---- critical: rflag -> r-part (per-lane) -> epilogue -> publish
            if (tid < 16) flag_wait(&rflag[(bgrp*16 + tid)*16], (u32)t);
            __syncthreads();
            CBAR();
            #pragma unroll
            for (int ks = 16; ks < 18; ++ks) {               // r-part, 3-term
                const float* rr = xr + (size_t)(bgrp*16 + jl)*MW + (ks-16)*32 + q*8;
                f4 r0v = vld4(rr);
                f4 r1v = vld4(rr + 4);
                short8 ah, al; pack_hilo(r0v, r1v, ah, al);
                const u16* bks = bp0 + (size_t)ks*BSTEP;
                #pragma unroll
                for (int tl = 0; tl < 4; ++tl) {
                    short8 bh = *(const short8*)(bks + tl*256);
                    short8 bl = *(const short8*)(bks + tl*256 + 8);
                    acc[tl] = __builtin_amdgcn_mfma_f32_16x16x32_bf16(ah, bh, acc[tl], 0,0,0);
                    acc[tl] = __builtin_amdgcn_mfma_f32_16x16x32_bf16(al, bh, acc[tl], 0,0,0);
                    acc[tl] = __builtin_amdgcn_mfma_f32_16x16x32_bf16(ah, bl, acc[tl], 0,0,0);
                }
            }
            // epilogue: lane transforms its OWN gate, then quad shuffle;
            // cell state lives on gl==0 lanes only
            #pragma unroll
            for (int tl = 0; tl < 4; ++tl) {
                int j = colbase + tl*16 + jl;
                float bias = biasr[tl];
                #pragma unroll
                for (int rg = 0; rg < 4; ++rg) {
                    float gval = acc[tl][rg] + bias;
                    float tval = (gl == 2) ? tanhf(gval) : sigm(gval);
                    int base = lane & ~3;
                    float iv = __shfl(tval, base+0, 64);
                    float fv = __shfl(tval, base+1, 64);
                    float gv = __shfl(tval, base+2, 64);
                    float ov = __shfl(tval, base+3, 64);
                    if (gl == 0) {
                        float cn = fv*creg[tl*4+rg] + iv*gv;
                        creg[tl*4+rg] = cn;
                        float hn = ov*tanhf(cn);
                        int nloc = (j >> 2) - cgrp*128;
                        hst2[(q*4+rg)*128 + nloc] = hn;
                    }
                }
            }
            __syncthreads();
            {   // coalesced f4 publish of the h slice
                float* hw = hbuf + (t&1)*65536;
                int idx = tid*4;
                int brl = idx >> 7, nloc = idx & 127;
                f4 v = *(const f4*)&hst2[brl*128 + nloc];
                vst4(hw + (size_t)(bgrp*16 + brl)*CDIM + cgrp*128 + nloc, v);
            }
            VMDRAIN();
            __syncthreads();
            if (tid == 0) flag_set(&hflag[a*32], (u32)(t+1));

            // ---- off-path: out h write + emb-part prefetch for t+1 ----
            {
                int idx = tid*4;
                int brl = idx >> 7, nloc = idx & 127;
                f4 v = *(const f4*)&hst2[brl*128 + nloc];
                *(f4*)(out + ((size_t)(t*BSZ + bgrp*16 + brl))*ODIM + cgrp*128 + nloc) = v;
            }
            if (t + 1 < T_STEPS)
                emb_part(acc, embs + ((size_t)((t+1)*BSZ + bA))*IDIM + q*8, bp0);
        }
    }
}

// ---------------- launch ----------------

#define OFF_WT     0u
#define OFF_BIASP  8912896u
#define OFF_WK     8921088u
#define OFF_KBIAS  9183232u
#define OFF_HBUF   9184256u
#define OFF_XR     9708544u
#define OFF_PAIR   9741312u
#define OFF_HFLAG  9872384u
#define OFF_RFLAG  9876480u
#define OFF_PFLAG  9884672u
#define WS_NEED    9901056u

extern "C" void kernel_launch(void* const* d_in, const int* in_sizes, int n_in,
                              void* d_out, int out_size, void* d_ws, size_t ws_size,
                              hipStream_t stream) {
    if (ws_size < (size_t)WS_NEED) return;

    const float* embs = (const float*)d_in[0];
    const float* w_ih = (const float*)d_in[1];
    const float* w_hh = (const float*)d_in[2];
    const float* b_ih = (const float*)d_in[3];
    const float* b_hh = (const float*)d_in[4];
    const float* h0   = (const float*)d_in[5];
    const float* c0   = (const float*)d_in[6];
    const float* r0   = (const float*)d_in[7];
    const float* mem0 = (const float*)d_in[8];
    const float* Wrk  = (const float*)d_in[9];
    const float* brk  = (const float*)d_in[10];
    const float* Wwk  = (const float*)d_in[11];
    const float* bwk  = (const float*)d_in[12];
    const float* We   = (const float*)d_in[13];
    const float* be   = (const float*)d_in[14];
    const float* Wa   = (const float*)d_in[15];
    const float* ba   = (const float*)d_in[16];

    char* ws = (char*)d_ws;
    u16*   WT    = (u16*)  (ws + OFF_WT);
    float* biasp = (float*)(ws + OFF_BIASP);
    u16*   Wk    = (u16*)  (ws + OFF_WK);
    float* kbias = (float*)(ws + OFF_KBIAS);
    float* hbuf  = (float*)(ws + OFF_HBUF);
    float* xrp   = (float*)(ws + OFF_XR);
    u32*   hflag = (u32*)  (ws + OFF_HFLAG);
    u32*   rflag = (u32*)  (ws + OFF_RFLAG);
    u32*   pflag = (u32*)  (ws + OFF_PFLAG);
    float* outp  = (float*)d_out;

    hipLaunchKernelGGL(prep_wt,   dim3(1088), dim3(256), 0, stream,
                       w_ih, w_hh, b_ih, b_hh, WT, biasp);
    hipLaunchKernelGGL(prep_misc, dim3(512),  dim3(256), 0, stream,
                       Wrk, Wwk, We, Wa, brk, bwk, be, ba, h0, r0,
                       Wk, kbias, hbuf, xrp, hflag, rflag, pflag);

    const float* embs_c = embs; const u16* WT_c = WT; const float* biasp_c = biasp;
    const u16* Wk_c = Wk; const float* kbias_c = kbias;
    const float* mem0_c = mem0; const float* c0_c = c0;
    void* kargs[] = { (void*)&embs_c, (void*)&WT_c, (void*)&biasp_c, (void*)&Wk_c,
                      (void*)&kbias_c, (void*)&hbuf, (void*)&xrp, (void*)&mem0_c,
                      (void*)&c0_c, (void*)&outp, (void*)&hflag, (void*)&rflag };
    hipLaunchCooperativeKernel((void*)mann_persist, dim3(160), dim3(512), kargs, 0, stream);
}

// Round 10
// 6401.304 us; speedup vs baseline: 1.9282x; 1.3538x over previous
//
#include <hip/hip_runtime.h>

// MANN/NTM encoder, MI355X persistent kernel, round 13.
// r12 post-mortem: A-role was per-CU L2-BW bound — each of 32 A-WGs streams
// its 2.2 MB WT slice every step (~15 us/step/CU at ~145 GB/s per-CU load
// BW). That was the unaccounted ~20 us/step. Fix: A 32 -> 128 WGs (grid 256,
// all CUs), each owning 128 gate-cols (0.55 MB/step -> ~4 us, hidden under
// B's body). Per-wave output = one 16x16 tile (acc 4 regs). DAG unchanged:
// B waits 16 hflags; A waits 16 sibling hflags + 16 rflags. B = r12 minus
// the redundant top-of-loop emb/a-key recompute (preloop + prefetch only).
// Flags agent-scope relaxed + vmcnt(0) drain; data plane volatile (UC).

#define T_STEPS 256
#define BSZ     128
#define IDIM    512
#define CDIM    512
#define MW      64
#define G4      2048
#define ODIM    576

typedef unsigned short u16;
typedef unsigned int   u32;
typedef short  short8  __attribute__((ext_vector_type(8)));
typedef float  floatx4 __attribute__((ext_vector_type(4)));
typedef float  f4      __attribute__((ext_vector_type(4)));

__device__ __forceinline__ float bf2f(u16 h){ return __uint_as_float(((u32)h)<<16); }
__device__ __forceinline__ u16   f2bf(float f){ u32 u = __float_as_uint(f); return (u16)((u + 0x7fffu + ((u>>16)&1u))>>16); }
__device__ __forceinline__ float sigm(float x){ return 1.f/(1.f+__expf(-x)); }

// coherent-point (L2-bypass) data movement — no cache maintenance
__device__ __forceinline__ f4 vld4(const float* p){ return *(const volatile f4*)p; }
__device__ __forceinline__ float vldf(const float* p){ return *(const volatile float*)p; }
__device__ __forceinline__ void vstf(float* p, float v){ *(volatile float*)p = v; }
__device__ __forceinline__ void vst4(float* p, f4 v){ *(volatile f4*)p = v; }

__device__ __forceinline__ void flag_set(u32* p, u32 v){
    __hip_atomic_store(p, v, __ATOMIC_RELAXED, __HIP_MEMORY_SCOPE_AGENT);
}
__device__ __forceinline__ void flag_wait(u32* p, u32 v){
    while (__hip_atomic_load(p, __ATOMIC_RELAXED, __HIP_MEMORY_SCOPE_AGENT) < v)
        __builtin_amdgcn_s_sleep(2);
}
#define VMDRAIN() asm volatile("s_waitcnt vmcnt(0)" ::: "memory")
#define CBAR()    asm volatile("" ::: "memory")

// ---------------- prep kernels ----------------

__global__ void prep_wt(const float* __restrict__ wih, const float* __restrict__ whh,
                        const float* __restrict__ bih, const float* __restrict__ bhh,
                        u16* __restrict__ WT, float* __restrict__ biasp){
    int idx = blockIdx.x*256 + threadIdx.x;          // 136*2048 = 278528
    if (idx >= 136*G4) return;
    int j  = idx & (G4-1);
    int kg = idx >> 11;
    int ro = (j&3)*512 + (j>>2);
    u32 ohi[4], olo[4];
    #pragma unroll
    for (int p=0;p<4;p++){
        int k0 = kg*8 + p*2;
        float v0 = (k0   < 576) ? wih[ro*576 + k0  ] : whh[ro*512 + k0   - 576];
        float v1 = (k0+1 < 576) ? wih[ro*576 + k0+1] : whh[ro*512 + k0+1 - 576];
        u16 h0b = f2bf(v0), h1b = f2bf(v1);
        u16 l0b = f2bf(v0 - bf2f(h0b)), l1b = f2bf(v1 - bf2f(h1b));
        ohi[p] = (u32)h0b | ((u32)h1b<<16);
        olo[p] = (u32)l0b | ((u32)l1b<<16);
    }
    *(uint4*)&WT[(size_t)idx*16]     = make_uint4(ohi[0],ohi[1],ohi[2],ohi[3]);
    *(uint4*)&WT[(size_t)idx*16 + 8] = make_uint4(olo[0],olo[1],olo[2],olo[3]);
    if (idx < G4) biasp[j] = bih[ro] + bhh[ro];
}

__global__ void prep_misc(const float* __restrict__ Wrk, const float* __restrict__ Wwk,
                          const float* __restrict__ We,  const float* __restrict__ Wa,
                          const float* __restrict__ brk, const float* __restrict__ bwk,
                          const float* __restrict__ be,  const float* __restrict__ ba,
                          const float* __restrict__ h0,  const float* __restrict__ r0,
                          u16* __restrict__ Wk, float* __restrict__ kb,
                          float* __restrict__ hbuf, float* __restrict__ xr,
                          u32* __restrict__ hflag, u32* __restrict__ rflag){
    int idx = blockIdx.x*256 + threadIdx.x;          // grid 512*256 = 131072
    if (idx < 32768) {
        int d4 = idx >> 8, k = idx & 255;
        const float* src = (k<64)? Wrk + k*512 : (k<128)? Wwk + (k-64)*512
                         : (k<192)? We + (k-128)*512 : Wa + (k-192)*512;
        u32 a = (u32)f2bf(src[d4*4+0]) | ((u32)f2bf(src[d4*4+1])<<16);
        u32 b = (u32)f2bf(src[d4*4+2]) | ((u32)f2bf(src[d4*4+3])<<16);
        *(uint2*)&Wk[(size_t)idx*4] = make_uint2(a,b);
    } else if (idx < 33024) {
        int k = idx - 32768;
        kb[k] = (k<64)? brk[k] : (k<128)? bwk[k-64] : (k<192)? be[k-128] : ba[k-192];
    } else if (idx < 98560) {
        int i = idx - 33024;
        hbuf[65536 + i] = h0[i & 511];               // slot 1 = h_{-1}
    } else if (idx < 106752) {
        int i = idx - 98560;
        xr[i] = r0[i & 63];
    } else if (idx < 108800) {
        hflag[idx - 106752] = 0u;                    // 2048 u32
    } else if (idx < 110848) {
        rflag[idx - 108800] = 0u;                    // 2048 u32
    }
}

// ---------------- persistent kernel ----------------

__device__ __forceinline__ short8 pack_hi(f4 a, f4 b){
    union { short8 s; u16 u[8]; } r;
    r.u[0]=f2bf(a[0]); r.u[1]=f2bf(a[1]); r.u[2]=f2bf(a[2]); r.u[3]=f2bf(a[3]);
    r.u[4]=f2bf(b[0]); r.u[5]=f2bf(b[1]); r.u[6]=f2bf(b[2]); r.u[7]=f2bf(b[3]);
    return r.s;
}
__device__ __forceinline__ void pack_hilo(f4 a, f4 b, short8& hh, short8& ll){
    union { short8 s; u16 u[8]; } H, L;
    float v[8] = {a[0],a[1],a[2],a[3],b[0],b[1],b[2],b[3]};
    #pragma unroll
    for (int i=0;i<8;i++){ u16 hb = f2bf(v[i]); H.u[i]=hb; L.u[i]=f2bf(v[i]-bf2f(hb)); }
    hh = H.s; ll = L.s;
}

// fused 2-value block reductions over 512 threads (8 waves)
__device__ __forceinline__ void blkMax2(float& va, float& vb, float* red){
    #pragma unroll
    for (int o=32;o;o>>=1){ va = fmaxf(va, __shfl_xor(va,o,64)); vb = fmaxf(vb, __shfl_xor(vb,o,64)); }
    int wv = threadIdx.x >> 6;
    if ((threadIdx.x & 63) == 0){ red[wv] = va; red[8+wv] = vb; }
    __syncthreads();
    float ra = red[0], rb = red[8];
    #pragma unroll
    for (int i=1;i<8;i++){ ra = fmaxf(ra, red[i]); rb = fmaxf(rb, red[8+i]); }
    va = ra; vb = rb;
}
__device__ __forceinline__ void blkSum2(float& va, float& vb, float* red){
    #pragma unroll
    for (int o=32;o;o>>=1){ va += __shfl_xor(va,o,64); vb += __shfl_xor(vb,o,64); }
    int wv = threadIdx.x >> 6;
    if ((threadIdx.x & 63) == 0){ red[wv] = va; red[8+wv] = vb; }
    __syncthreads();
    float ra = red[0], rb = red[8];
    #pragma unroll
    for (int i=1;i<8;i++){ ra += red[i]; rb += red[8+i]; }
    va = ra; vb = rb;
}

// one key's 256-dim half-GEMV from an LDS-staged source, Wk L2-resident
__device__ __forceinline__ float key_gemv(const float* src, const u16* __restrict__ Wk,
                                          int key, int d0){
    const uint2* wp = (const uint2*)Wk;
    float a0=0.f, a1=0.f, a2=0.f, a3=0.f;
    #pragma unroll 8
    for (int dd = 0; dd < 256; dd += 4) {
        uint2 wv2 = wp[((d0+dd)>>2)*256 + key];
        a0 += src[d0+dd+0]*bf2f((u16)(wv2.x & 0xffffu));
        a1 += src[d0+dd+1]*bf2f((u16)(wv2.x >> 16));
        a2 += src[d0+dd+2]*bf2f((u16)(wv2.y & 0xffffu));
        a3 += src[d0+dd+3]*bf2f((u16)(wv2.y >> 16));
    }
    return (a0+a1)+(a2+a3);
}

#define BSTEP ((size_t)(4*G4*16))

// emb-part, single 16x16 tile (K=512, 2-term); zero-inits acc.
__device__ __forceinline__ void emb_part1(floatx4& acc, const float* embrow,
                                          const u16* __restrict__ bp0){
    acc[0]=0.f; acc[1]=0.f; acc[2]=0.f; acc[3]=0.f;
    #pragma unroll 2
    for (int ks = 0; ks < 16; ++ks) {
        f4 e0 = *(const f4*)(embrow + ks*32);
        f4 e1 = *(const f4*)(embrow + ks*32 + 4);
        short8 af = pack_hi(e0, e1);
        const u16* bks = bp0 + (size_t)ks*BSTEP;
        short8 bh = *(const short8*)(bks);
        short8 bl = *(const short8*)(bks + 8);
        acc = __builtin_amdgcn_mfma_f32_16x16x32_bf16(af, bh, acc, 0,0,0);
        acc = __builtin_amdgcn_mfma_f32_16x16x32_bf16(af, bl, acc, 0,0,0);
    }
}

__launch_bounds__(512)
__global__ void mann_persist(const float* __restrict__ embs, const u16* __restrict__ WT,
                             const float* __restrict__ biasp, const u16* __restrict__ Wk,
                             const float* __restrict__ kbias,
                             float* __restrict__ hbuf, float* __restrict__ xr,
                             const float* __restrict__ mem0, const float* __restrict__ c0,
                             float* __restrict__ out,
                             u32* __restrict__ hflag, u32* __restrict__ rflag){
    __shared__ __align__(16) char smraw[140800];
    float* sp = (float*)smraw;
    const int w = blockIdx.x;
    const int tid = threadIdx.x;
    if (w >= 256) return;

    if (w < 128) {
        // ================= B role: one WG per batch, memory in VGPRs =========
        float* part = sp;            // [512][65]  read-reduction staging
        float* gsc  = sp + 33280;    // [512] GEMV partials / reduce scratch
        float* keys = sp + 33792;    // [256] k_r | k_w | e | a
        float* red  = sp + 34048;    // [32]
        float* hb   = sp + 34080;    // [512] h_t
        float* ebb  = sp + 34592;    // [512] emb_t
        const int b = w;
        const int key = tid & 255, kh = tid >> 8, d0 = kh*256;
        const int n0 = tid*2;        // this thread owns memory rows n0, n0+1

        float m0[64], m1[64];
        #pragma unroll
        for (int m4=0;m4<16;m4++){
            f4 v0 = *(const f4*)(mem0 + (size_t)n0*64 + m4*4);
            f4 v1 = *(const f4*)(mem0 + (size_t)(n0+1)*64 + m4*4);
            #pragma unroll
            for (int j=0;j<4;j++){ m0[m4*4+j] = v0[j]; m1[m4*4+j] = v1[j]; }
        }

        // preloop: emb_0 + a-key partials for step 0
        ebb[tid] = embs[(size_t)b*IDIM + tid];
        __syncthreads();
        if (key >= 192) gsc[tid] = key_gemv(ebb, Wk, key, d0);

        for (int t = 0; t < T_STEPS; ++t) {
            if (tid < 16) flag_wait(&hflag[((b>>4)*16 + tid)*16], (u32)(t+1));
            __syncthreads();
            CBAR();
            hb[tid] = vldf(hbuf + (t&1)*65536 + b*CDIM + tid);
            __syncthreads();
            if (key < 192) gsc[tid] = key_gemv(hb, Wk, key, d0);
            __syncthreads();
            if (tid < 256) {
                float acc = kbias[tid] + gsc[tid] + gsc[tid+256];
                if (tid >= 192)      acc = tanhf(acc);
                else if (tid >= 128) acc = sigm(acc);
                keys[tid] = acc;
            }
            __syncthreads();

            // content scores for both keys from register-resident memory rows
            float s0r=0.f, s0w=0.f, s1r=0.f, s1w=0.f;
            #pragma unroll
            for (int m4=0;m4<16;m4++){
                f4 kr = *(const f4*)&keys[m4*4];
                f4 kw = *(const f4*)&keys[64 + m4*4];
                #pragma unroll
                for (int j=0;j<4;j++){
                    s0r += m0[m4*4+j]*kr[j]; s1r += m1[m4*4+j]*kr[j];
                    s0w += m0[m4*4+j]*kw[j]; s1w += m1[m4*4+j]*kw[j];
                }
            }
            float Mr = fmaxf(s0r, s1r), Mw = fmaxf(s0w, s1w);
            blkMax2(Mr, Mw, red);
            float e0r = __expf(s0r - Mr), e1r = __expf(s1r - Mr);
            float e0w = __expf(s0w - Mw), e1w = __expf(s1w - Mw);
            float Sr = e0r + e1r, Sw = e0w + e1w;
            blkSum2(Sr, Sw, red + 16);

            // read partials -> padded LDS tile (stride 65: conflict-free)
            float* prow = part + tid*65;
            #pragma unroll
            for (int m=0;m<64;m++) prow[m] = e0r*m0[m] + e1r*m1[m];
            __syncthreads();
            {
                int mm = tid & 63, blk = tid >> 6;
                const float* pb2 = part + (size_t)blk*64*65 + mm;
                float s = 0.f;
                #pragma unroll
                for (int r=0;r<64;r++) s += pb2[r*65];
                gsc[tid] = s;
            }
            __syncthreads();
            float rv = 0.f;
            if (tid < 64) {
                #pragma unroll
                for (int k=0;k<8;k++) rv += gsc[k*64 + tid];
                rv /= Sr;
                vstf(xr + b*MW + tid, rv);
            }
            VMDRAIN();                                  // writers are wave 0
            if (tid == 0) flag_set(&rflag[b*16], (u32)(t+1));

            // off-path: out r write + erase/add update (registers only)
            if (tid < 64)
                out[((size_t)(t*BSZ + b))*ODIM + 512 + tid] = rv;
            float iSw = 1.f / Sw;
            float w0 = e0w*iSw, w1 = e1w*iSw;
            #pragma unroll
            for (int m4=0;m4<16;m4++){
                f4 ev = *(const f4*)&keys[128 + m4*4];
                f4 av = *(const f4*)&keys[192 + m4*4];
                #pragma unroll
                for (int j=0;j<4;j++){
                    m0[m4*4+j] = m0[m4*4+j]*(1.f - w0*ev[j]) + w0*av[j];
                    m1[m4*4+j] = m1[m4*4+j]*(1.f - w1*ev[j]) + w1*av[j];
                }
            }
            // emb prefetch + a-key partials for t+1 (barrier also separates
            // the read-reduce gsc reads from the a-key gsc writes)
            if (t + 1 < T_STEPS) {
                ebb[tid] = embs[((size_t)((t+1)*BSZ + b))*IDIM + tid];
                __syncthreads();
                if (key >= 192) gsc[tid] = key_gemv(ebb, Wk, key, d0);
            }
        }
    } else {
        // ================= A role: 128 gates-GEMM WGs (128 cols each) ========
        float* hst  = sp;            // [16][516] staged h_{t-1}
        float* hst2 = sp + 8256;     // [16][32]  h_t slice (this WG's 32 n's)
        const int a = w - 128, bgrp = a >> 4, cseg = a & 15;
        const int lane = tid & 63, wv = tid >> 6, jl = lane & 15, q = lane >> 4;
        const int jcol = cseg*128 + wv*16 + jl;    // this lane's packed column
        const int gl = jl & 3;                     // lane's gate type (i,f,g,o)
        const u16* bp0 = WT + ((size_t)q*G4 + jcol)*16;

        const float bias = biasp[jcol];
        float creg[4];                             // valid on gl==0 lanes only
        {
            float cv = c0[jcol >> 2];
            creg[0]=cv; creg[1]=cv; creg[2]=cv; creg[3]=cv;
        }
        floatx4 acc;
        emb_part1(acc, embs + (size_t)(bgrp*16 + jl)*IDIM + q*8, bp0);  // t=0

        for (int t = 0; t < T_STEPS; ++t) {
            // ---- speculative: overlaps B's body of step t-1 ----
            if (tid < 16) flag_wait(&hflag[(bgrp*16 + tid)*16], (u32)t);
            __syncthreads();
            CBAR();
            {   // stage h_{t-1}: 16 batches x 512, one volatile burst
                const float* hsrc = hbuf + ((t+1)&1)*65536 + (size_t)bgrp*16*CDIM;
                #pragma unroll
                for (int p=0;p<4;p++){
                    int idx = p*2048 + tid*4;
                    f4 v = vld4(hsrc + idx);
                    *(f4*)&hst[(idx>>9)*516 + (idx&511)] = v;
                }
            }
            __syncthreads();
            #pragma unroll 2
            for (int ks = 18; ks < 34; ++ks) {              // h-part, 3-term
                int d = (ks-18)*32 + q*8;
                f4 h0v = *(const f4*)&hst[jl*516 + d];
                f4 h1v = *(const f4*)&hst[jl*516 + d + 4];
                short8 ah, al; pack_hilo(h0v, h1v, ah, al);
                const u16* bks = bp0 + (size_t)ks*BSTEP;
                short8 bh = *(const short8*)(bks);
                short8 bl = *(const short8*)(bks + 8);
                acc = __builtin_amdgcn_mfma_f32_16x16x32_bf16(ah, bh, acc, 0,0,0);
                acc = __builtin_amdgcn_mfma_f32_16x16x32_bf16(al, bh, acc, 0,0,0);
                acc = __builtin_amdgcn_mfma_f32_16x16x32_bf16(ah, bl, acc, 0,0,0);
            }

            // ---- critical: rflag -> r-part (per-lane) -> epilogue -> publish
            if (tid < 16) flag_wait(&rflag[(bgrp*16 + tid)*16], (u32)t);
            __syncthreads();
            CBAR();
            #pragma unroll
            for (int ks = 16; ks < 18; ++ks) {               // r-part, 3-term
                const float* rr = xr + (size_t)(bgrp*16 + jl)*MW + (ks-16)*32 + q*8;
                f4 r0v = vld4(rr);
                f4 r1v = vld4(rr + 4);
                short8 ah, al; pack_hilo(r0v, r1v, ah, al);
                const u16* bks = bp0 + (size_t)ks*BSTEP;
                short8 bh = *(const short8*)(bks);
                short8 bl = *(const short8*)(bks + 8);
                acc = __builtin_amdgcn_mfma_f32_16x16x32_bf16(ah, bh, acc, 0,0,0);
                acc = __builtin_amdgcn_mfma_f32_16x16x32_bf16(al, bh, acc, 0,0,0);
                acc = __builtin_amdgcn_mfma_f32_16x16x32_bf16(ah, bl, acc, 0,0,0);
            }
            // epilogue: lane transforms its OWN gate, quad shuffle; cell state
            // on gl==0 lanes. quad = (g=0..3) of one n (j = 4n+g consecutive).
            #pragma unroll
            for (int rg = 0; rg < 4; ++rg) {
                float gval = acc[rg] + bias;
                float tval = (gl == 2) ? tanhf(gval) : sigm(gval);
                int base = lane & ~3;
                float iv = __shfl(tval, base+0, 64);
                float fv = __shfl(tval, base+1, 64);
                float gv = __shfl(tval, base+2, 64);
                float ov = __shfl(tval, base+3, 64);
                if (gl == 0) {
                    float cn = fv*creg[rg] + iv*gv;
                    creg[rg] = cn;
                    float hn = ov*tanhf(cn);
                    int nloc = wv*4 + (jl >> 2);             // [0,32)
                    hst2[(q*4+rg)*32 + nloc] = hn;
                }
            }
            __syncthreads();
            if (tid < 128) {   // coalesced f4 publish of the 16x32 h slice
                float* hw = hbuf + (t&1)*65536;
                int idx = tid*4;
                int brl = tid >> 3, nloc = idx & 31;
                f4 v = *(const f4*)&hst2[brl*32 + nloc];
                vst4(hw + (size_t)(bgrp*16 + brl)*CDIM + cseg*32 + nloc, v);
            }
            VMDRAIN();
            __syncthreads();
            if (tid == 0) flag_set(&hflag[a*16], (u32)(t+1));

            // ---- off-path: out h write + emb-part prefetch for t+1 ----
            if (tid < 128) {
                int idx = tid*4;
                int brl = tid >> 3, nloc = idx & 31;
                f4 v = *(const f4*)&hst2[brl*32 + nloc];
                *(f4*)(out + ((size_t)(t*BSZ + bgrp*16 + brl))*ODIM + cseg*32 + nloc) = v;
            }
            if (t + 1 < T_STEPS)
                emb_part1(acc, embs + ((size_t)((t+1)*BSZ + bgrp*16 + jl))*IDIM + q*8, bp0);
        }
    }
}

// ---------------- launch ----------------

#define OFF_WT     0u
#define OFF_BIASP  8912896u
#define OFF_WK     8921088u
#define OFF_KBIAS  9183232u
#define OFF_HBUF   9184256u
#define OFF_XR     9708544u
#define OFF_HFLAG  9741312u
#define OFF_RFLAG  9749504u
#define WS_NEED    9901056u

extern "C" void kernel_launch(void* const* d_in, const int* in_sizes, int n_in,
                              void* d_out, int out_size, void* d_ws, size_t ws_size,
                              hipStream_t stream) {
    if (ws_size < (size_t)WS_NEED) return;

    const float* embs = (const float*)d_in[0];
    const float* w_ih = (const float*)d_in[1];
    const float* w_hh = (const float*)d_in[2];
    const float* b_ih = (const float*)d_in[3];
    const float* b_hh = (const float*)d_in[4];
    const float* h0   = (const float*)d_in[5];
    const float* c0   = (const float*)d_in[6];
    const float* r0   = (const float*)d_in[7];
    const float* mem0 = (const float*)d_in[8];
    const float* Wrk  = (const float*)d_in[9];
    const float* brk  = (const float*)d_in[10];
    const float* Wwk  = (const float*)d_in[11];
    const float* bwk  = (const float*)d_in[12];
    const float* We   = (const float*)d_in[13];
    const float* be   = (const float*)d_in[14];
    const float* Wa   = (const float*)d_in[15];
    const float* ba   = (const float*)d_in[16];

    char* ws = (char*)d_ws;
    u16*   WT    = (u16*)  (ws + OFF_WT);
    float* biasp = (float*)(ws + OFF_BIASP);
    u16*   Wk    = (u16*)  (ws + OFF_WK);
    float* kbias = (float*)(ws + OFF_KBIAS);
    float* hbuf  = (float*)(ws + OFF_HBUF);
    float* xrp   = (float*)(ws + OFF_XR);
    u32*   hflag = (u32*)  (ws + OFF_HFLAG);
    u32*   rflag = (u32*)  (ws + OFF_RFLAG);
    float* outp  = (float*)d_out;

    hipLaunchKernelGGL(prep_wt,   dim3(1088), dim3(256), 0, stream,
                       w_ih, w_hh, b_ih, b_hh, WT, biasp);
    hipLaunchKernelGGL(prep_misc, dim3(512),  dim3(256), 0, stream,
                       Wrk, Wwk, We, Wa, brk, bwk, be, ba, h0, r0,
                       Wk, kbias, hbuf, xrp, hflag, rflag);

    const float* embs_c = embs; const u16* WT_c = WT; const float* biasp_c = biasp;
    const u16* Wk_c = Wk; const float* kbias_c = kbias;
    const float* mem0_c = mem0; const float* c0_c = c0;
    void* kargs[] = { (void*)&embs_c, (void*)&WT_c, (void*)&biasp_c, (void*)&Wk_c,
                      (void*)&kbias_c, (void*)&hbuf, (void*)&xrp, (void*)&mem0_c,
                      (void*)&c0_c, (void*)&outp, (void*)&hflag, (void*)&rflag };
    hipLaunchCooperativeKernel((void*)mann_persist, dim3(256), dim3(512), kargs, 0, stream);
}